// Round 8
// baseline (662.275 us; speedup 1.0000x reference)
//
#include <hip/hip_runtime.h>

typedef unsigned short u16;
typedef unsigned int u32;
typedef __attribute__((ext_vector_type(4))) float f32x4;
typedef __attribute__((ext_vector_type(8))) short short8;

#define HWD 56
#define HW2 3136
#define C_IN 128
#define K_OUT 256
#define N_IMG 32
#define CHW_IN 401408
#define CHW_OUT 802816
#define PIX 100352
#define WQ_N 294912
// xt3: [cq4][gRow 1872][58][c32] bf16. Image n = gRows n*58 .. n*58+57 (row 0 & 57 zero).
#define GROWS 1872
#define XROW 1856              // 58*32 elems per gRow
#define XPLANE (GROWS * XROW)  // 3,474,432 elems per cq plane
#define NR 12                  // staged gRows per block (max span 10 + margin)
#define BCHUNKS 2784           // NR*58*4 16B-chunks
#define NSLICE 1568            // 392 blocks * 4 wn
#define CV_OFF 33554432u
#define WS_NEED_BF16 (CV_OFF + (size_t)PIX * K_OUT * 2)

__device__ __forceinline__ u16 f2bf(float f) {
    u32 u = __float_as_uint(f);
    u32 r = u + 0x7FFFu + ((u >> 16) & 1u);
    return (u16)(r >> 16);
}

__device__ __forceinline__ void glds16(const u16* g, u16* l) {
    __builtin_amdgcn_global_load_lds(
        (const __attribute__((address_space(1))) void*)g,
        (__attribute__((address_space(3))) void*)l, 16, 0, 0);
}

__global__ void maxabs_k(const float* __restrict__ w, u32* __restrict__ wsmax) {
    float m = 0.f;
    for (int i = blockIdx.x * blockDim.x + threadIdx.x; i < WQ_N; i += gridDim.x * blockDim.x)
        m = fmaxf(m, fabsf(w[i]));
    for (int off = 32; off; off >>= 1)
        m = fmaxf(m, __shfl_xor(m, off));
    __shared__ float sm[4];
    int lane = threadIdx.x & 63, wid = threadIdx.x >> 6;
    if (lane == 0) sm[wid] = m;
    __syncthreads();
    if (threadIdx.x == 0) {
        float mm = fmaxf(fmaxf(sm[0], sm[1]), fmaxf(sm[2], sm[3]));
        atomicMax(wsmax, __float_as_uint(mm));
    }
}

// wqt4: [kt36][oct4][m256][8]; kt = cq*9+tap; c = cq*32 + oct*8 + j
__global__ void quant_t_k4(const float* __restrict__ w, const u32* __restrict__ wsmax,
                           u16* __restrict__ wqt4) {
    int o = blockIdx.x * 256 + threadIdx.x;
    if (o >= WQ_N) return;
    int j = o & 7;
    int m = (o >> 3) & 255;
    int oct = (o >> 11) & 3;
    int kt = o >> 13;
    int cq = kt / 9, tap = kt - cq * 9;
    int c = cq * 32 + oct * 8 + j;
    float scale = __uint_as_float(wsmax[0]) / 7.0f;
    float q = rintf(w[(m * 128 + c) * 9 + tap] / scale);
    q = fminf(fmaxf(q, -7.0f), 7.0f);
    wqt4[o] = f2bf(q * scale);
}

// zero halos of xt3: full rows {n*58, n*58+57, 1856..1871} + data-row cols {0,57}
__global__ void halo_zero(u16* __restrict__ xt3) {
    int i = blockIdx.x * 256 + threadIdx.x;   // 131,584 total, grid exact
    u32 addr;
    if (i < 74240) {
        int rowIdx = i / 928, rem = i - rowIdx * 928;
        int cq = rem / 232, c = rem - cq * 232;
        int row = rowIdx < 64 ? (rowIdx >> 1) * 58 + (rowIdx & 1) * 57 : 1856 + (rowIdx - 64);
        addr = (u32)cq * XPLANE + row * XROW + c * 8;
    } else {
        int j = i - 74240;
        int rowd = j >> 5, rem = j & 31;
        int side = rem >> 4, cq = (rem >> 2) & 3, o4 = rem & 3;
        int n = rowd / 56, h = rowd - n * 56;
        int row = n * 58 + 1 + h, col = side * 57;
        addr = (u32)cq * XPLANE + (row * 58 + col) * 32 + o4 * 8;
    }
    *(uint4*)(xt3 + addr) = (uint4){0, 0, 0, 0};
}

// x (NCHW f32) -> xt3 interior
__global__ __launch_bounds__(256) void pad_transpose(const float* __restrict__ x,
                                                     u16* __restrict__ xt3) {
    __shared__ float T[128][57];
    const int tid = threadIdx.x;
    const int n = blockIdx.x / HWD;
    const int h = blockIdx.x - n * HWD;
    const float* srow = x + (size_t)n * CHW_IN + h * HWD;
    #pragma unroll
    for (int it = 0; it < 7; ++it) {
        int i = tid + it * 256;
        int c = i / 14, q = i - c * 14;
        float4 v = *(const float4*)(srow + c * HW2 + q * 4);
        T[c][q * 4 + 0] = v.x; T[c][q * 4 + 1] = v.y;
        T[c][q * 4 + 2] = v.z; T[c][q * 4 + 3] = v.w;
    }
    __syncthreads();
    const int gRow = n * 58 + 1 + h;
    #pragma unroll
    for (int it = 0; it < 4; ++it) {
        int i = tid + it * 256;
        if (i < 56 * 16) {
            int w = i >> 4, oc = i & 15;
            int cq = oc >> 2, o4 = oc & 3;
            union { u16 us[8]; uint4 v4; } pk;
            #pragma unroll
            for (int j = 0; j < 8; ++j) pk.us[j] = f2bf(T[oc * 8 + j][w]);
            *(uint4*)(xt3 + (size_t)cq * XPLANE + (gRow * 58 + (w + 1)) * 32 + o4 * 8) = pk.v4;
        }
    }
}

// ===== conv: BM256 x BN256 x BK32, tap-reuse B neighborhood, A 3-buf counted-vmcnt =====
// 8 waves (2 wm x 4 wn), per-wave 128ch x 64px. Swapped MFMA: D row=px, col=ch.
// LDS: B neighborhood [696 px][40 pad elems] = 55,680B @0; A 3x16KB @55,680. Epilogue T reuses.
template <bool BF16OUT>
__global__ __launch_bounds__(512, 2) void conv_m(const u16* __restrict__ xt3,
                                                 const u16* __restrict__ wqt4,
                                                 float* __restrict__ out,
                                                 u16* __restrict__ cvout,
                                                 float* __restrict__ P) {
    __shared__ __align__(16) u16 lds[52416];   // 104,832 B
    const int tid = threadIdx.x;
    const int lane = tid & 63;
    const int w8 = tid >> 6;
    const int wm = w8 >> 2, wn = w8 & 3;
    const int fr = lane & 15, fq = lane >> 4;
    // XCD swizzle: 392 = 8*49 bijective
    const int nt = (blockIdx.x & 7) * 49 + (blockIdx.x >> 3);
    const int p0 = nt * 256;
    const int R0 = (p0 / HW2) * 58 + (p0 % HW2) / HWD;   // gRow(p0) - 1

    // per-lane B bases (elem units; pixel pitch 40 elems = 80B)
    int bElem[4];
    #pragma unroll
    for (int ni = 0; ni < 4; ++ni) {
        int px = p0 + wn * 64 + ni * 16 + fr;
        int img = px / HW2, hw = px - img * HW2;
        int gr = img * 58 + 1 + hw / HWD;
        int pixLin = (gr - R0) * 58 + (hw % HWD) + 1;
        bElem[ni] = (pixLin - 59) * 40 + fq * 8;          // >= 0; tap imm = (it*58+u)*80 bytes
    }
    const int aBase = 27840 + fq * 2048 + (wm * 128 + fr) * 8;  // elem; + u*8192 + mi*128

#define GATE2() asm volatile("s_waitcnt vmcnt(2)" ::: "memory")
#define GATE0() asm volatile("s_waitcnt vmcnt(0)" ::: "memory")
#define BAR() __builtin_amdgcn_s_barrier()

    f32x4 acc[8][4];
    #pragma unroll
    for (int a = 0; a < 8; ++a)
        #pragma unroll
        for (int b = 0; b < 4; ++b)
            acc[a][b] = (f32x4){0.f, 0.f, 0.f, 0.f};

    #pragma unroll 1
    for (int cq = 0; cq < 4; ++cq) {
        // ---- stage B neighborhood for this cq (regs -> padded LDS) ----
        {
            const u16* bsrc = xt3 + (size_t)cq * XPLANE + (size_t)R0 * XROW;
            uint4 breg[6];
            #pragma unroll
            for (int i = 0; i < 6; ++i) {
                int c = tid + i * 512;
                if (c < BCHUNKS) breg[i] = *(const uint4*)(bsrc + c * 8);
            }
            if (cq == 0) {   // A prologue: kt 0 -> buf0, kt 1 -> buf1
                glds16(wqt4 + tid * 8,              &lds[27840 + tid * 8]);
                glds16(wqt4 + (tid + 512) * 8,      &lds[27840 + (tid + 512) * 8]);
                glds16(wqt4 + 8192 + tid * 8,       &lds[27840 + 8192 + tid * 8]);
                glds16(wqt4 + 8192 + (tid + 512) * 8, &lds[27840 + 8192 + (tid + 512) * 8]);
            }
            #pragma unroll
            for (int i = 0; i < 6; ++i) {
                int c = tid + i * 512;
                if (c < BCHUNKS)
                    *(uint4*)&lds[(c >> 2) * 40 + (c & 3) * 8] = breg[i];
            }
        }
        __syncthreads();   // drains vmcnt+lgkm: B visible, A bufs for first steps landed

        #pragma unroll
        for (int it = 0; it < 3; ++it) {
            #pragma unroll
            for (int u = 0; u < 3; ++u) {
                const int kt = cq * 9 + it * 3 + u;
                // stage A for kt+2 into buf (u+2)%3
                if (kt + 2 < 36) {
                    const u16* ga = wqt4 + (kt + 2) * 8192;
                    u16* da = &lds[27840 + ((u + 2) % 3) * 8192];
                    glds16(ga + tid * 8, da + tid * 8);
                    glds16(ga + (tid + 512) * 8, da + (tid + 512) * 8);
                }
                // fragments
                short8 pf[4], wf[8];
                #pragma unroll
                for (int ni = 0; ni < 4; ++ni)
                    pf[ni] = *(const short8*)&lds[bElem[ni] + it * 2320 + u * 40];
                #pragma unroll
                for (int mi = 0; mi < 8; ++mi)
                    wf[mi] = *(const short8*)&lds[aBase + u * 8192 + mi * 128];
                __builtin_amdgcn_s_setprio(1);
                #pragma unroll
                for (int mi = 0; mi < 8; ++mi)
                    #pragma unroll
                    for (int ni = 0; ni < 4; ++ni)
                        acc[mi][ni] = __builtin_amdgcn_mfma_f32_16x16x32_bf16(
                            pf[ni], wf[mi], acc[mi][ni], 0, 0, 0);  // D row=px, col=ch
                __builtin_amdgcn_s_setprio(0);
                if (kt < 34) GATE2();
                else if (kt == 34) GATE0();
                BAR();
            }
        }
    }

    // ---- fused per-channel partials: lane's ch = wm*128 + mi*16 + fr (col) ----
    const int slice = nt * 4 + wn;
    #pragma unroll
    for (int mi = 0; mi < 8; ++mi) {
        float s = 0.f, q = 0.f;
        #pragma unroll
        for (int ni = 0; ni < 4; ++ni)
            #pragma unroll
            for (int j = 0; j < 4; ++j) {
                float v = acc[mi][ni][j];
                s += v; q += v * v;
            }
        s += __shfl_xor(s, 16); s += __shfl_xor(s, 32);
        q += __shfl_xor(q, 16); q += __shfl_xor(q, 32);
        if (fq == 0) {
            int ch = wm * 128 + mi * 16 + fr;
            float* dst = P + ((size_t)ch * NSLICE + slice) * 2;
            dst[0] = s; dst[1] = q;
        }
    }

    if (BF16OUT) {
        // two passes: T[lch 128][px 264pad] bf16 (67,584B, reuses lds)
        u16* T = lds;
        #pragma unroll 1
        for (int p = 0; p < 2; ++p) {
            __syncthreads();
            #pragma unroll
            for (int c2 = 0; c2 < 4; ++c2) {
                const int mi = p * 4 + c2;
                const int lch = wm * 64 + c2 * 16 + fr;
                #pragma unroll
                for (int ni = 0; ni < 4; ++ni) {
                    union { u16 h[4]; uint2 v; } pk;
                    #pragma unroll
                    for (int j = 0; j < 4; ++j) pk.h[j] = f2bf(acc[mi][ni][j]);
                    *(uint2*)&T[lch * 264 + wn * 64 + ni * 16 + fq * 4] = pk.v;
                }
            }
            __syncthreads();
            #pragma unroll
            for (int i = 0; i < 8; ++i) {
                int chunk = tid + i * 512;
                int lch = chunk >> 5, pxc = chunk & 31;
                uint4 v = *(const uint4*)&T[lch * 264 + pxc * 8];
                int ch = (lch >> 6) * 128 + p * 64 + (lch & 63);
                *(uint4*)&cvout[(size_t)ch * PIX + p0 + pxc * 8] = v;
            }
        }
    } else {
        #pragma unroll
        for (int mi = 0; mi < 8; ++mi) {
            int ch = wm * 128 + mi * 16 + fr;
            #pragma unroll
            for (int ni = 0; ni < 4; ++ni)
                #pragma unroll
                for (int j = 0; j < 4; ++j) {
                    int px = p0 + wn * 64 + ni * 16 + fq * 4 + j;
                    int n = px / HW2, hw = px - n * HW2;
                    out[(size_t)n * CHW_OUT + (size_t)ch * HW2 + hw] = acc[mi][ni][j];
                }
        }
    }
#undef GATE2
#undef GATE0
#undef BAR
}

__global__ void stats_fin(const float* __restrict__ P, const float* __restrict__ gamma,
                          const float* __restrict__ beta, float* __restrict__ stats) {
    int ch = blockIdx.x;
    int tid = threadIdx.x;
    float s = 0.f, q = 0.f;
    const float* base = P + (size_t)ch * NSLICE * 2;
    for (int i = tid; i < NSLICE; i += 256) {
        float2 v = *(const float2*)(base + i * 2);
        s += v.x; q += v.y;
    }
    for (int m = 32; m; m >>= 1) { s += __shfl_xor(s, m); q += __shfl_xor(q, m); }
    __shared__ float ss[4], qs[4];
    int l = tid & 63, w = tid >> 6;
    if (l == 0) { ss[w] = s; qs[w] = q; }
    __syncthreads();
    if (tid == 0) {
        float S = ss[0] + ss[1] + ss[2] + ss[3];
        float Q = qs[0] + qs[1] + qs[2] + qs[3];
        float mean = S / (float)PIX;
        float var = Q / (float)PIX - mean * mean;
        float inv = gamma[ch] * rsqrtf(var + 1e-5f);
        stats[2 * ch] = inv;
        stats[2 * ch + 1] = beta[ch] - mean * inv;
    }
}

// cvout [ch][global-pix] bf16 -> out NCHW f32
__global__ void bn_relu_nchw(const u16* __restrict__ cvout, float* __restrict__ out,
                             const float* __restrict__ stats) {
    const int b = blockIdx.x;            // 256 ch * 49 groups
    const int ch = b / 49, g = b - ch * 49;
    const float inv = stats[2 * ch], sh = stats[2 * ch + 1];
    const int p8 = (g * 256 + threadIdx.x) * 8;
    short8 v = *(const short8*)&cvout[(size_t)ch * PIX + p8];
    const int n = p8 / HW2;
    const int hw = p8 - n * HW2;
    float* dst = out + ((size_t)n * K_OUT + ch) * HW2 + hw;
    f32x4 o0, o1;
    #pragma unroll
    for (int j = 0; j < 4; ++j) {
        float a = __uint_as_float(((u32)(u16)v[j]) << 16);
        float bb = __uint_as_float(((u32)(u16)v[j + 4]) << 16);
        o0[j] = fmaxf(a * inv + sh, 0.f);
        o1[j] = fmaxf(bb * inv + sh, 0.f);
    }
    *(f32x4*)dst = o0;
    *(f32x4*)(dst + 4) = o1;
}

__global__ void bn_relu_f32(float* __restrict__ out, const float* __restrict__ stats) {
    const int n4 = ((size_t)N_IMG * K_OUT * HW2) / 4;
    int stride = gridDim.x * blockDim.x;
    for (int i = blockIdx.x * blockDim.x + threadIdx.x; i < n4; i += stride) {
        int ch = (i / (HW2 / 4)) & (K_OUT - 1);
        float inv = stats[2 * ch], sh = stats[2 * ch + 1];
        f32x4 v = ((f32x4*)out)[i];
        #pragma unroll
        for (int j = 0; j < 4; ++j)
            v[j] = fmaxf(v[j] * inv + sh, 0.f);
        ((f32x4*)out)[i] = v;
    }
}

extern "C" void kernel_launch(void* const* d_in, const int* in_sizes, int n_in,
                              void* d_out, int out_size, void* d_ws, size_t ws_size,
                              hipStream_t stream) {
    const float* x = (const float*)d_in[0];
    const float* w = (const float*)d_in[1];
    const float* gamma = (const float*)d_in[2];
    const float* beta = (const float*)d_in[3];
    float* out = (float*)d_out;

    char* ws = (char*)d_ws;
    u32* wsmax = (u32*)ws;                         // [0,64)
    float* stats = (float*)(ws + 64);              // 2KB
    u16* wqt4 = (u16*)(ws + 4096);                 // 589,824 B
    float* P = (float*)(ws + 1048576u);            // 3,211,264 B
    u16* xt3 = (u16*)(ws + 4325376u);              // 27,795,456 B (ends 32,120,832)
    u16* cvout = (u16*)(ws + CV_OFF);              // 51,380,224 B
    const bool bf16path = (ws_size >= WS_NEED_BF16);

    hipMemsetAsync(wsmax, 0, 64, stream);
    maxabs_k<<<128, 256, 0, stream>>>(w, wsmax);
    quant_t_k4<<<WQ_N / 256, 256, 0, stream>>>(w, wsmax, wqt4);
    halo_zero<<<514, 256, 0, stream>>>(xt3);
    pad_transpose<<<N_IMG * HWD, 256, 0, stream>>>(x, xt3);
    if (bf16path) {
        conv_m<true><<<392, 512, 0, stream>>>(xt3, wqt4, out, cvout, P);
        stats_fin<<<K_OUT, 256, 0, stream>>>(P, gamma, beta, stats);
        bn_relu_nchw<<<K_OUT * 49, 256, 0, stream>>>(cvout, out, stats);
    } else {
        conv_m<false><<<392, 512, 0, stream>>>(xt3, wqt4, out, cvout, P);
        stats_fin<<<K_OUT, 256, 0, stream>>>(P, gamma, beta, stats);
        bn_relu_f32<<<4096, 256, 0, stream>>>(out, stats);
    }
}

// Round 9
// 150.300 us; speedup vs baseline: 4.4064x; 4.4064x over previous
//
#include <hip/hip_runtime.h>

typedef unsigned short u16;
typedef unsigned int u32;
typedef __attribute__((ext_vector_type(4))) float f32x4;
typedef __attribute__((ext_vector_type(8))) short short8;

#define HWD 56
#define HW2 3136
#define C_IN 128
#define K_OUT 256
#define N_IMG 32
#define CHW_IN 401408
#define CHW_OUT 802816
#define PIX 100352
#define WQ_N 294912
// xt3: [cq4][gRow 1872][58][c32] bf16. Image n = gRows n*58 .. n*58+57 (row 0 & 57 zero).
#define GROWS 1872
#define XROW 1856              // 58*32 elems per gRow
#define XPLANE (GROWS * XROW)  // 3,474,432 elems per cq plane
#define NR 12                  // staged gRows per block (max span 10 + margin)
#define BCHUNKS 2784           // NR*58*4 16B-chunks
#define NSLICE 1568            // 392 blocks * 4 wn
#define CV_OFF 33554432u
#define WS_NEED_BF16 (CV_OFF + (size_t)PIX * K_OUT * 2)

__device__ __forceinline__ u16 f2bf(float f) {
    u32 u = __float_as_uint(f);
    u32 r = u + 0x7FFFu + ((u >> 16) & 1u);
    return (u16)(r >> 16);
}

__device__ __forceinline__ void glds16(const u16* g, u16* l) {
    __builtin_amdgcn_global_load_lds(
        (const __attribute__((address_space(1))) void*)g,
        (__attribute__((address_space(3))) void*)l, 16, 0, 0);
}

__global__ void maxabs_k(const float* __restrict__ w, u32* __restrict__ wsmax) {
    float m = 0.f;
    for (int i = blockIdx.x * blockDim.x + threadIdx.x; i < WQ_N; i += gridDim.x * blockDim.x)
        m = fmaxf(m, fabsf(w[i]));
    for (int off = 32; off; off >>= 1)
        m = fmaxf(m, __shfl_xor(m, off));
    __shared__ float sm[4];
    int lane = threadIdx.x & 63, wid = threadIdx.x >> 6;
    if (lane == 0) sm[wid] = m;
    __syncthreads();
    if (threadIdx.x == 0) {
        float mm = fmaxf(fmaxf(sm[0], sm[1]), fmaxf(sm[2], sm[3]));
        atomicMax(wsmax, __float_as_uint(mm));
    }
}

// wqt4: [kt36][oct4][m256][8]; kt = cq*9+tap; c = cq*32 + oct*8 + j
__global__ void quant_t_k4(const float* __restrict__ w, const u32* __restrict__ wsmax,
                           u16* __restrict__ wqt4) {
    int o = blockIdx.x * 256 + threadIdx.x;
    if (o >= WQ_N) return;
    int j = o & 7;
    int m = (o >> 3) & 255;
    int oct = (o >> 11) & 3;
    int kt = o >> 13;
    int cq = kt / 9, tap = kt - cq * 9;
    int c = cq * 32 + oct * 8 + j;
    float scale = __uint_as_float(wsmax[0]) / 7.0f;
    float q = rintf(w[(m * 128 + c) * 9 + tap] / scale);
    q = fminf(fmaxf(q, -7.0f), 7.0f);
    wqt4[o] = f2bf(q * scale);
}

// zero halos of xt3: full rows {n*58, n*58+57, 1856..1871} + data-row cols {0,57}
__global__ void halo_zero(u16* __restrict__ xt3) {
    int i = blockIdx.x * 256 + threadIdx.x;   // 131,584 total
    u32 addr;
    if (i < 74240) {
        int rowIdx = i / 928, rem = i - rowIdx * 928;
        int cq = rem / 232, c = rem - cq * 232;
        int row = rowIdx < 64 ? (rowIdx >> 1) * 58 + (rowIdx & 1) * 57 : 1856 + (rowIdx - 64);
        addr = (u32)cq * XPLANE + row * XROW + c * 8;
    } else {
        int j = i - 74240;
        int rowd = j >> 5, rem = j & 31;
        int side = rem >> 4, cq = (rem >> 2) & 3, o4 = rem & 3;
        int n = rowd / 56, h = rowd - n * 56;
        int row = n * 58 + 1 + h, col = side * 57;
        addr = (u32)cq * XPLANE + (row * 58 + col) * 32 + o4 * 8;
    }
    *(uint4*)(xt3 + addr) = (uint4){0, 0, 0, 0};
}

// x (NCHW f32) -> xt3 interior
__global__ __launch_bounds__(256) void pad_transpose(const float* __restrict__ x,
                                                     u16* __restrict__ xt3) {
    __shared__ float T[128][57];
    const int tid = threadIdx.x;
    const int n = blockIdx.x / HWD;
    const int h = blockIdx.x - n * HWD;
    const float* srow = x + (size_t)n * CHW_IN + h * HWD;
    #pragma unroll
    for (int it = 0; it < 7; ++it) {
        int i = tid + it * 256;
        int c = i / 14, q = i - c * 14;
        float4 v = *(const float4*)(srow + c * HW2 + q * 4);
        T[c][q * 4 + 0] = v.x; T[c][q * 4 + 1] = v.y;
        T[c][q * 4 + 2] = v.z; T[c][q * 4 + 3] = v.w;
    }
    __syncthreads();
    const int gRow = n * 58 + 1 + h;
    #pragma unroll
    for (int it = 0; it < 4; ++it) {
        int i = tid + it * 256;
        if (i < 56 * 16) {
            int w = i >> 4, oc = i & 15;
            int cq = oc >> 2, o4 = oc & 3;
            union { u16 us[8]; uint4 v4; } pk;
            #pragma unroll
            for (int j = 0; j < 8; ++j) pk.us[j] = f2bf(T[oc * 8 + j][w]);
            *(uint4*)(xt3 + (size_t)cq * XPLANE + (gRow * 58 + (w + 1)) * 32 + o4 * 8) = pk.v4;
        }
    }
}

// ===== conv: BM256 x BN256 x BK32, tap-reuse B neighborhood, A 3-buf counted-vmcnt =====
// 8 waves (2 wm x 4 wn), per-wave 128ch x 64px. Swapped MFMA: D row=px, col=ch.
// LDS: B neighborhood [696 px][40 pad elems] = 55,680B @0; A 3x16KB @55,680.
template <bool BF16OUT>
__global__ __launch_bounds__(512, 2) void conv_m(const u16* __restrict__ xt3,
                                                 const u16* __restrict__ wqt4,
                                                 float* __restrict__ out,
                                                 u16* __restrict__ cvout,
                                                 float* __restrict__ P) {
    __shared__ __align__(16) u16 lds[52416];   // 104,832 B
    const int tid = threadIdx.x;
    const int lane = tid & 63;
    const int w8 = tid >> 6;
    const int wm = w8 >> 2, wn = w8 & 3;
    const int fr = lane & 15, fq = lane >> 4;
    // XCD swizzle: 392 = 8*49 bijective
    const int nt = (blockIdx.x & 7) * 49 + (blockIdx.x >> 3);
    const int p0 = nt * 256;
    const int R0 = (p0 / HW2) * 58 + (p0 % HW2) / HWD;   // gRow(p0) - 1

    // per-lane B bases (elem units; pixel pitch 40 elems = 80B)
    int bElem[4];
    #pragma unroll
    for (int ni = 0; ni < 4; ++ni) {
        int px = p0 + wn * 64 + ni * 16 + fr;
        int img = px / HW2, hw = px - img * HW2;
        int gr = img * 58 + 1 + hw / HWD;
        int pixLin = (gr - R0) * 58 + (hw % HWD) + 1;
        bElem[ni] = (pixLin - 59) * 40 + fq * 8;          // >= 0; tap imm = (it*58+u)*80 bytes
    }
    const int aBase = 27840 + fq * 2048 + (wm * 128 + fr) * 8;  // elem; + u*8192 + mi*128

#define GATE2() asm volatile("s_waitcnt vmcnt(2)" ::: "memory")
#define GATE0() asm volatile("s_waitcnt vmcnt(0)" ::: "memory")
#define BAR() __builtin_amdgcn_s_barrier()

    f32x4 acc[8][4];
    #pragma unroll
    for (int a = 0; a < 8; ++a)
        #pragma unroll
        for (int b = 0; b < 4; ++b)
            acc[a][b] = (f32x4){0.f, 0.f, 0.f, 0.f};

    #pragma unroll 1
    for (int cq = 0; cq < 4; ++cq) {
        // ---- stage B neighborhood for this cq (regs -> padded LDS) ----
        {
            const u16* bsrc = xt3 + (size_t)cq * XPLANE + (size_t)R0 * XROW;
            uint4 breg[6];
            #pragma unroll
            for (int i = 0; i < 6; ++i) {
                int c = tid + i * 512;
                if (c < BCHUNKS) breg[i] = *(const uint4*)(bsrc + c * 8);
            }
            if (cq == 0) {   // A prologue: kt 0 -> buf0, kt 1 -> buf1
                glds16(wqt4 + tid * 8,              &lds[27840 + tid * 8]);
                glds16(wqt4 + (tid + 512) * 8,      &lds[27840 + (tid + 512) * 8]);
                glds16(wqt4 + 8192 + tid * 8,       &lds[27840 + 8192 + tid * 8]);
                glds16(wqt4 + 8192 + (tid + 512) * 8, &lds[27840 + 8192 + (tid + 512) * 8]);
            }
            #pragma unroll
            for (int i = 0; i < 6; ++i) {
                int c = tid + i * 512;
                if (c < BCHUNKS)
                    *(uint4*)&lds[(c >> 2) * 40 + (c & 3) * 8] = breg[i];
            }
        }
        __syncthreads();   // drains vmcnt+lgkm: B visible, A bufs for first steps landed

        #pragma unroll
        for (int it = 0; it < 3; ++it) {
            #pragma unroll
            for (int u = 0; u < 3; ++u) {
                const int kt = cq * 9 + it * 3 + u;
                // stage A for kt+2 into buf (u+2)%3
                if (kt + 2 < 36) {
                    const u16* ga = wqt4 + (kt + 2) * 8192;
                    u16* da = &lds[27840 + ((u + 2) % 3) * 8192];
                    glds16(ga + tid * 8, da + tid * 8);
                    glds16(ga + (tid + 512) * 8, da + (tid + 512) * 8);
                }
                // fragments: pf once, wf in two halves (register-pressure cap)
                short8 pf[4], wf[4];
                #pragma unroll
                for (int ni = 0; ni < 4; ++ni)
                    pf[ni] = *(const short8*)&lds[bElem[ni] + it * 2320 + u * 40];
                #pragma unroll
                for (int mi = 0; mi < 4; ++mi)
                    wf[mi] = *(const short8*)&lds[aBase + u * 8192 + mi * 128];
                __builtin_amdgcn_s_setprio(1);
                #pragma unroll
                for (int mi = 0; mi < 4; ++mi)
                    #pragma unroll
                    for (int ni = 0; ni < 4; ++ni)
                        acc[mi][ni] = __builtin_amdgcn_mfma_f32_16x16x32_bf16(
                            pf[ni], wf[mi], acc[mi][ni], 0, 0, 0);  // D row=px, col=ch
                __builtin_amdgcn_s_setprio(0);
                #pragma unroll
                for (int mi = 0; mi < 4; ++mi)
                    wf[mi] = *(const short8*)&lds[aBase + u * 8192 + (mi + 4) * 128];
                __builtin_amdgcn_s_setprio(1);
                #pragma unroll
                for (int mi = 0; mi < 4; ++mi)
                    #pragma unroll
                    for (int ni = 0; ni < 4; ++ni)
                        acc[mi + 4][ni] = __builtin_amdgcn_mfma_f32_16x16x32_bf16(
                            pf[ni], wf[mi], acc[mi + 4][ni], 0, 0, 0);
                __builtin_amdgcn_s_setprio(0);
                if (kt < 34) GATE2();
                else if (kt == 34) GATE0();
                BAR();
            }
        }
    }

    // ---- fused per-channel partials: lane's ch = wm*128 + mi*16 + fr (col) ----
    const int slice = nt * 4 + wn;
    #pragma unroll
    for (int mi = 0; mi < 8; ++mi) {
        float s = 0.f, q = 0.f;
        #pragma unroll
        for (int ni = 0; ni < 4; ++ni)
            #pragma unroll
            for (int j = 0; j < 4; ++j) {
                float v = acc[mi][ni][j];
                s += v; q += v * v;
            }
        s += __shfl_xor(s, 16); s += __shfl_xor(s, 32);
        q += __shfl_xor(q, 16); q += __shfl_xor(q, 32);
        if (fq == 0) {
            int ch = wm * 128 + mi * 16 + fr;
            float* dst = P + ((size_t)ch * NSLICE + slice) * 2;
            dst[0] = s; dst[1] = q;
        }
    }

    if (BF16OUT) {
        // two fully-unrolled passes: T[lch 128][px 264pad] bf16 (67,584B, reuses lds)
        u16* T = lds;
        #pragma unroll
        for (int p = 0; p < 2; ++p) {      // COMPILE-TIME p: acc indices static (rule #20)
            __syncthreads();
            #pragma unroll
            for (int c2 = 0; c2 < 4; ++c2) {
                const int lch = wm * 64 + c2 * 16 + fr;
                #pragma unroll
                for (int ni = 0; ni < 4; ++ni) {
                    union { u16 h[4]; uint2 v; } pk;
                    #pragma unroll
                    for (int j = 0; j < 4; ++j) pk.h[j] = f2bf(acc[p * 4 + c2][ni][j]);
                    *(uint2*)&T[lch * 264 + wn * 64 + ni * 16 + fq * 4] = pk.v;
                }
            }
            __syncthreads();
            #pragma unroll
            for (int i = 0; i < 8; ++i) {
                int chunk = tid + i * 512;
                int lch = chunk >> 5, pxc = chunk & 31;
                uint4 v = *(const uint4*)&T[lch * 264 + pxc * 8];
                int ch = (lch >> 6) * 128 + p * 64 + (lch & 63);
                *(uint4*)&cvout[(size_t)ch * PIX + p0 + pxc * 8] = v;
            }
        }
    } else {
        #pragma unroll
        for (int mi = 0; mi < 8; ++mi) {
            int ch = wm * 128 + mi * 16 + fr;
            #pragma unroll
            for (int ni = 0; ni < 4; ++ni)
                #pragma unroll
                for (int j = 0; j < 4; ++j) {
                    int px = p0 + wn * 64 + ni * 16 + fq * 4 + j;
                    int n = px / HW2, hw = px - n * HW2;
                    out[(size_t)n * CHW_OUT + (size_t)ch * HW2 + hw] = acc[mi][ni][j];
                }
        }
    }
#undef GATE2
#undef GATE0
#undef BAR
}

__global__ void stats_fin(const float* __restrict__ P, const float* __restrict__ gamma,
                          const float* __restrict__ beta, float* __restrict__ stats) {
    int ch = blockIdx.x;
    int tid = threadIdx.x;
    float s = 0.f, q = 0.f;
    const float* base = P + (size_t)ch * NSLICE * 2;
    for (int i = tid; i < NSLICE; i += 256) {
        float2 v = *(const float2*)(base + i * 2);
        s += v.x; q += v.y;
    }
    for (int m = 32; m; m >>= 1) { s += __shfl_xor(s, m); q += __shfl_xor(q, m); }
    __shared__ float ss[4], qs[4];
    int l = tid & 63, w = tid >> 6;
    if (l == 0) { ss[w] = s; qs[w] = q; }
    __syncthreads();
    if (tid == 0) {
        float S = ss[0] + ss[1] + ss[2] + ss[3];
        float Q = qs[0] + qs[1] + qs[2] + qs[3];
        float mean = S / (float)PIX;
        float var = Q / (float)PIX - mean * mean;
        float inv = gamma[ch] * rsqrtf(var + 1e-5f);
        stats[2 * ch] = inv;
        stats[2 * ch + 1] = beta[ch] - mean * inv;
    }
}

// cvout [ch][global-pix] bf16 -> out NCHW f32
__global__ void bn_relu_nchw(const u16* __restrict__ cvout, float* __restrict__ out,
                             const float* __restrict__ stats) {
    const int b = blockIdx.x;            // 256 ch * 49 groups
    const int ch = b / 49, g = b - ch * 49;
    const float inv = stats[2 * ch], sh = stats[2 * ch + 1];
    const int p8 = (g * 256 + threadIdx.x) * 8;
    short8 v = *(const short8*)&cvout[(size_t)ch * PIX + p8];
    const int n = p8 / HW2;
    const int hw = p8 - n * HW2;
    float* dst = out + ((size_t)n * K_OUT + ch) * HW2 + hw;
    f32x4 o0, o1;
    #pragma unroll
    for (int j = 0; j < 4; ++j) {
        float a = __uint_as_float(((u32)(u16)v[j]) << 16);
        float bb = __uint_as_float(((u32)(u16)v[j + 4]) << 16);
        o0[j] = fmaxf(a * inv + sh, 0.f);
        o1[j] = fmaxf(bb * inv + sh, 0.f);
    }
    *(f32x4*)dst = o0;
    *(f32x4*)(dst + 4) = o1;
}

__global__ void bn_relu_f32(float* __restrict__ out, const float* __restrict__ stats) {
    const int n4 = ((size_t)N_IMG * K_OUT * HW2) / 4;
    int stride = gridDim.x * blockDim.x;
    for (int i = blockIdx.x * blockDim.x + threadIdx.x; i < n4; i += stride) {
        int ch = (i / (HW2 / 4)) & (K_OUT - 1);
        float inv = stats[2 * ch], sh = stats[2 * ch + 1];
        f32x4 v = ((f32x4*)out)[i];
        #pragma unroll
        for (int j = 0; j < 4; ++j)
            v[j] = fmaxf(v[j] * inv + sh, 0.f);
        ((f32x4*)out)[i] = v;
    }
}

extern "C" void kernel_launch(void* const* d_in, const int* in_sizes, int n_in,
                              void* d_out, int out_size, void* d_ws, size_t ws_size,
                              hipStream_t stream) {
    const float* x = (const float*)d_in[0];
    const float* w = (const float*)d_in[1];
    const float* gamma = (const float*)d_in[2];
    const float* beta = (const float*)d_in[3];
    float* out = (float*)d_out;

    char* ws = (char*)d_ws;
    u32* wsmax = (u32*)ws;                         // [0,64)
    float* stats = (float*)(ws + 64);              // 2KB
    u16* wqt4 = (u16*)(ws + 4096);                 // 589,824 B
    float* P = (float*)(ws + 1048576u);            // 3,211,264 B
    u16* xt3 = (u16*)(ws + 4325376u);              // 27,795,456 B (ends 32,120,832)
    u16* cvout = (u16*)(ws + CV_OFF);              // 51,380,224 B
    const bool bf16path = (ws_size >= WS_NEED_BF16);

    hipMemsetAsync(wsmax, 0, 64, stream);
    maxabs_k<<<128, 256, 0, stream>>>(w, wsmax);
    quant_t_k4<<<WQ_N / 256, 256, 0, stream>>>(w, wsmax, wqt4);
    halo_zero<<<514, 256, 0, stream>>>(xt3);
    pad_transpose<<<N_IMG * HWD, 256, 0, stream>>>(x, xt3);
    if (bf16path) {
        conv_m<true><<<392, 512, 0, stream>>>(xt3, wqt4, out, cvout, P);
        stats_fin<<<K_OUT, 256, 0, stream>>>(P, gamma, beta, stats);
        bn_relu_nchw<<<K_OUT * 49, 256, 0, stream>>>(cvout, out, stats);
    } else {
        conv_m<false><<<392, 512, 0, stream>>>(xt3, wqt4, out, cvout, P);
        stats_fin<<<K_OUT, 256, 0, stream>>>(P, gamma, beta, stats);
        bn_relu_f32<<<4096, 256, 0, stream>>>(out, stats);
    }
}

// Round 10
// 146.288 us; speedup vs baseline: 4.5272x; 1.0274x over previous
//
#include <hip/hip_runtime.h>

typedef unsigned short u16;
typedef unsigned int u32;
typedef __attribute__((ext_vector_type(4))) float f32x4;
typedef __attribute__((ext_vector_type(8))) short short8;

#define HWD 56
#define HW2 3136
#define C_IN 128
#define K_OUT 256
#define N_IMG 32
#define CHW_IN 401408
#define CHW_OUT 802816
#define PIX 100352
#define WQ_N 294912
// xt3: [cq4][gRow 1872][58][c32] bf16. Image n = gRows n*58 .. n*58+57 (rows n*58, n*58+57 zero).
#define GROWS 1872
#define XROW 1856              // 58*32 elems per gRow
#define XPLANE (GROWS * XROW)
#define NR 10                  // staged gRows per block (exact: span<=7 data+cross, +2 outer halo)
#define BCHUNKS 2320           // NR*58*4 16B-chunks of source
#define BPITCH 40              // LDS elems per pixel (80B, 16B-aligned, ~2-way banks)
#define BELEMS 23200           // NR*58*BPITCH
#define NSLICE 1568            // 392 nt * 4 wn
#define CV_OFF 33554432u
#define WS_NEED_BF16 (CV_OFF + (size_t)PIX * K_OUT * 2)

__device__ __forceinline__ u16 f2bf(float f) {
    u32 u = __float_as_uint(f);
    u32 r = u + 0x7FFFu + ((u >> 16) & 1u);
    return (u16)(r >> 16);
}

__device__ __forceinline__ void glds16(const u16* g, u16* l) {
    __builtin_amdgcn_global_load_lds(
        (const __attribute__((address_space(1))) void*)g,
        (__attribute__((address_space(3))) void*)l, 16, 0, 0);
}

__global__ void maxabs_k(const float* __restrict__ w, u32* __restrict__ wsmax) {
    float m = 0.f;
    for (int i = blockIdx.x * blockDim.x + threadIdx.x; i < WQ_N; i += gridDim.x * blockDim.x)
        m = fmaxf(m, fabsf(w[i]));
    for (int off = 32; off; off >>= 1)
        m = fmaxf(m, __shfl_xor(m, off));
    __shared__ float sm[4];
    int lane = threadIdx.x & 63, wid = threadIdx.x >> 6;
    if (lane == 0) sm[wid] = m;
    __syncthreads();
    if (threadIdx.x == 0) {
        float mm = fmaxf(fmaxf(sm[0], sm[1]), fmaxf(sm[2], sm[3]));
        atomicMax(wsmax, __float_as_uint(mm));
    }
}

// wqt: [kt36][mt2][oct4][m128][8]; kt = cq*9 + tap; c = cq*32 + oct*8 + j; m = mt*128 + mrow
__global__ void quant_t_k5(const float* __restrict__ w, const u32* __restrict__ wsmax,
                           u16* __restrict__ wqt) {
    int o = blockIdx.x * 256 + threadIdx.x;
    if (o >= WQ_N) return;
    int j = o & 7;
    int mrow = (o >> 3) & 127;
    int oct = (o >> 10) & 3;
    int mt = (o >> 12) & 1;
    int kt = o >> 13;
    int cq = kt / 9, tap = kt - cq * 9;
    int c = cq * 32 + oct * 8 + j;
    int m = mt * 128 + mrow;
    float scale = __uint_as_float(wsmax[0]) / 7.0f;
    float q = rintf(w[(m * 128 + c) * 9 + tap] / scale);
    q = fminf(fmaxf(q, -7.0f), 7.0f);
    wqt[o] = f2bf(q * scale);
}

// zero halos of xt3: full rows {n*58, n*58+57, 1856..1871} + data-row cols {0,57}
__global__ void halo_zero(u16* __restrict__ xt3) {
    int i = blockIdx.x * 256 + threadIdx.x;   // 131,584 total
    u32 addr;
    if (i < 74240) {
        int rowIdx = i / 928, rem = i - rowIdx * 928;
        int cq = rem / 232, c = rem - cq * 232;
        int row = rowIdx < 64 ? (rowIdx >> 1) * 58 + (rowIdx & 1) * 57 : 1856 + (rowIdx - 64);
        addr = (u32)cq * XPLANE + row * XROW + c * 8;
    } else {
        int j = i - 74240;
        int rowd = j >> 5, rem = j & 31;
        int side = rem >> 4, cq = (rem >> 2) & 3, o4 = rem & 3;
        int n = rowd / 56, h = rowd - n * 56;
        int row = n * 58 + 1 + h, col = side * 57;
        addr = (u32)cq * XPLANE + (row * 58 + col) * 32 + o4 * 8;
    }
    *(uint4*)(xt3 + addr) = (uint4){0, 0, 0, 0};
}

// x (NCHW f32) -> xt3 interior
__global__ __launch_bounds__(256) void pad_transpose(const float* __restrict__ x,
                                                     u16* __restrict__ xt3) {
    __shared__ float T[128][57];
    const int tid = threadIdx.x;
    const int n = blockIdx.x / HWD;
    const int h = blockIdx.x - n * HWD;
    const float* srow = x + (size_t)n * CHW_IN + h * HWD;
    #pragma unroll
    for (int it = 0; it < 7; ++it) {
        int i = tid + it * 256;
        int c = i / 14, q = i - c * 14;
        float4 v = *(const float4*)(srow + c * HW2 + q * 4);
        T[c][q * 4 + 0] = v.x; T[c][q * 4 + 1] = v.y;
        T[c][q * 4 + 2] = v.z; T[c][q * 4 + 3] = v.w;
    }
    __syncthreads();
    const int gRow = n * 58 + 1 + h;
    #pragma unroll
    for (int it = 0; it < 4; ++it) {
        int i = tid + it * 256;
        if (i < 56 * 16) {
            int w = i >> 4, oc = i & 15;
            int cq = oc >> 2, o4 = oc & 3;
            union { u16 us[8]; uint4 v4; } pk;
            #pragma unroll
            for (int j = 0; j < 8; ++j) pk.us[j] = f2bf(T[oc * 8 + j][w]);
            *(uint4*)(xt3 + (size_t)cq * XPLANE + (gRow * 58 + (w + 1)) * 32 + o4 * 8) = pk.v4;
        }
    }
}

// ===== conv: block 128ch(mt) x 256px, 4 waves (128x64), per-cq B neighborhood, A 3-buf =====
// 784 blocks (2/CU). LDS: B [580 px][40] = 46,400B @0; A 3x8KB @23,200 elems. 70,976B total.
template <bool BF16OUT>
__global__ __launch_bounds__(256, 2) void conv_m(const u16* __restrict__ xt3,
                                                 const u16* __restrict__ wqt,
                                                 float* __restrict__ out,
                                                 u16* __restrict__ cvout,
                                                 float* __restrict__ P) {
    __shared__ __align__(16) u16 lds[35488];   // 70,976 B
    const int tid = threadIdx.x;
    const int lane = tid & 63;
    const int w4 = tid >> 6;           // wave = px quarter (wn)
    const int fr = lane & 15, fq = lane >> 4;
    // XCD swizzle: 784 = 8*98 bijective; mt-pairs (same nt) adjacent on same XCD
    const int swz = (blockIdx.x & 7) * 98 + (blockIdx.x >> 3);
    const int nt = swz >> 1, mt = swz & 1;
    const int p0 = nt * 256;
    const int R0 = (p0 / HW2) * 58 + (p0 % HW2) / HWD;   // gRow(p0) - 1

    // per-lane B fragment bases (elem units, pixel pitch 40)
    int bElem[4];
    #pragma unroll
    for (int ni = 0; ni < 4; ++ni) {
        int px = p0 + w4 * 64 + ni * 16 + fr;
        int img = px / HW2, hw = px - img * HW2;
        int gr = img * 58 + 1 + hw / HWD;
        int pixLin = (gr - R0) * 58 + (hw % HWD) + 1;
        bElem[ni] = (pixLin - 59) * BPITCH + fq * 8;   // tap (r,s): + (r*58+s)*BPITCH
    }

#define ABUF(b) (&lds[BELEMS + (b) * 4096])
#define STAGE_A(kt_, b_) do {                                              \
        const u16* ga_ = wqt + (size_t)(((kt_) * 2 + mt)) * 4096;          \
        glds16(ga_ + tid * 8,         ABUF(b_) + tid * 8);                 \
        glds16(ga_ + (tid + 256) * 8, ABUF(b_) + (tid + 256) * 8);         \
    } while (0)
#define GATE2() asm volatile("s_waitcnt vmcnt(2)" ::: "memory")
#define GATE0() asm volatile("s_waitcnt vmcnt(0)" ::: "memory")
#define BAR() __builtin_amdgcn_s_barrier()

    f32x4 acc[8][4];
    #pragma unroll
    for (int a = 0; a < 8; ++a)
        #pragma unroll
        for (int b = 0; b < 4; ++b)
            acc[a][b] = (f32x4){0.f, 0.f, 0.f, 0.f};

    STAGE_A(0, 0);
    STAGE_A(1, 1);

    #pragma unroll 1
    for (int cq = 0; cq < 4; ++cq) {
        // ---- stage B neighborhood (global -> regs -> 80B-pitch LDS), once per 9 kt ----
        {
            const u16* bsrc = xt3 + (size_t)cq * XPLANE + (size_t)R0 * XROW;
            uint4 breg[10];
            #pragma unroll
            for (int i = 0; i < 10; ++i) {
                int c = tid + i * 256;
                if (c < BCHUNKS) breg[i] = *(const uint4*)(bsrc + c * 8);
            }
            GATE0();   // B regs ready; pending A glds also drained (kt reads safe)
            #pragma unroll
            for (int i = 0; i < 10; ++i) {
                int c = tid + i * 256;
                if (c < BCHUNKS)
                    *(uint4*)&lds[(c >> 2) * BPITCH + (c & 3) * 8] = breg[i];
            }
        }
        __syncthreads();

        #pragma unroll
        for (int it = 0; it < 3; ++it) {
            #pragma unroll
            for (int u = 0; u < 3; ++u) {
                const int tt = it * 3 + u;          // compile-time
                const int kt = cq * 9 + tt;
                if (kt + 2 < 36) STAGE_A(kt + 2, (tt + 2) % 3);
                // fragments (read buf tt%3; cq*9 ≡ 0 mod 3)
                short8 pf[4], wf[4];
                #pragma unroll
                for (int ni = 0; ni < 4; ++ni)
                    pf[ni] = *(const short8*)&lds[bElem[ni] + (it * 58 + u) * BPITCH];
                #pragma unroll
                for (int mi = 0; mi < 4; ++mi)
                    wf[mi] = *(const short8*)&(ABUF(tt % 3)[fq * 1024 + mi * 128 + fr * 8]);
                __builtin_amdgcn_s_setprio(1);
                #pragma unroll
                for (int mi = 0; mi < 4; ++mi)
                    #pragma unroll
                    for (int ni = 0; ni < 4; ++ni)
                        acc[mi][ni] = __builtin_amdgcn_mfma_f32_16x16x32_bf16(
                            pf[ni], wf[mi], acc[mi][ni], 0, 0, 0);  // D row=px, col=ch
                __builtin_amdgcn_s_setprio(0);
                #pragma unroll
                for (int mi = 0; mi < 4; ++mi)
                    wf[mi] = *(const short8*)&(ABUF(tt % 3)[fq * 1024 + (mi + 4) * 128 + fr * 8]);
                __builtin_amdgcn_s_setprio(1);
                #pragma unroll
                for (int mi = 0; mi < 4; ++mi)
                    #pragma unroll
                    for (int ni = 0; ni < 4; ++ni)
                        acc[mi + 4][ni] = __builtin_amdgcn_mfma_f32_16x16x32_bf16(
                            pf[ni], wf[mi], acc[mi + 4][ni], 0, 0, 0);
                __builtin_amdgcn_s_setprio(0);
                if (kt < 34) GATE2();
                else if (kt == 34) GATE0();
                BAR();
            }
        }
    }

    // ---- fused per-channel partials: ch = mt*128 + mi*16 + fr (D col) ----
    const int slice = nt * 4 + w4;
    #pragma unroll
    for (int mi = 0; mi < 8; ++mi) {
        float s = 0.f, q = 0.f;
        #pragma unroll
        for (int ni = 0; ni < 4; ++ni)
            #pragma unroll
            for (int j = 0; j < 4; ++j) {
                float v = acc[mi][ni][j];
                s += v; q += v * v;
            }
        s += __shfl_xor(s, 16); s += __shfl_xor(s, 32);
        q += __shfl_xor(q, 16); q += __shfl_xor(q, 32);
        if (fq == 0) {
            int ch = mt * 128 + mi * 16 + fr;
            float* dst = P + ((size_t)ch * NSLICE + slice) * 2;
            dst[0] = s; dst[1] = q;
        }
    }

    if (BF16OUT) {
        // two compile-time passes (rule #20): T[64 lch][264 pad] bf16 = 33,792B
        u16* T = lds;
        #pragma unroll
        for (int p = 0; p < 2; ++p) {
            __syncthreads();
            #pragma unroll
            for (int c2 = 0; c2 < 4; ++c2) {
                const int lch = c2 * 16 + fr;
                #pragma unroll
                for (int ni = 0; ni < 4; ++ni) {
                    union { u16 h[4]; uint2 v; } pk;
                    #pragma unroll
                    for (int j = 0; j < 4; ++j) pk.h[j] = f2bf(acc[p * 4 + c2][ni][j]);
                    *(uint2*)&T[lch * 264 + w4 * 64 + ni * 16 + fq * 4] = pk.v;
                }
            }
            __syncthreads();
            #pragma unroll
            for (int i = 0; i < 8; ++i) {
                int q = tid + i * 256;               // 2048 chunks: 64 lch x 32 pxc
                int lch = q >> 5, pxc = q & 31;
                uint4 v = *(const uint4*)&T[lch * 264 + pxc * 8];
                int ch = mt * 128 + p * 64 + lch;
                *(uint4*)&cvout[(size_t)ch * PIX + p0 + pxc * 8] = v;
            }
        }
    } else {
        #pragma unroll
        for (int mi = 0; mi < 8; ++mi) {
            int ch = mt * 128 + mi * 16 + fr;
            #pragma unroll
            for (int ni = 0; ni < 4; ++ni)
                #pragma unroll
                for (int j = 0; j < 4; ++j) {
                    int px = p0 + w4 * 64 + ni * 16 + fq * 4 + j;
                    int n = px / HW2, hw = px - n * HW2;
                    out[(size_t)n * CHW_OUT + (size_t)ch * HW2 + hw] = acc[mi][ni][j];
                }
        }
    }
#undef ABUF
#undef STAGE_A
#undef GATE2
#undef GATE0
#undef BAR
}

__global__ void stats_fin(const float* __restrict__ P, const float* __restrict__ gamma,
                          const float* __restrict__ beta, float* __restrict__ stats) {
    int ch = blockIdx.x;
    int tid = threadIdx.x;
    float s = 0.f, q = 0.f;
    const float* base = P + (size_t)ch * NSLICE * 2;
    for (int i = tid; i < NSLICE; i += 256) {
        float2 v = *(const float2*)(base + i * 2);
        s += v.x; q += v.y;
    }
    for (int m = 32; m; m >>= 1) { s += __shfl_xor(s, m); q += __shfl_xor(q, m); }
    __shared__ float ss[4], qs[4];
    int l = tid & 63, w = tid >> 6;
    if (l == 0) { ss[w] = s; qs[w] = q; }
    __syncthreads();
    if (tid == 0) {
        float S = ss[0] + ss[1] + ss[2] + ss[3];
        float Q = qs[0] + qs[1] + qs[2] + qs[3];
        float mean = S / (float)PIX;
        float var = Q / (float)PIX - mean * mean;
        float inv = gamma[ch] * rsqrtf(var + 1e-5f);
        stats[2 * ch] = inv;
        stats[2 * ch + 1] = beta[ch] - mean * inv;
    }
}

// cvout [ch][global-pix] bf16 -> out NCHW f32
__global__ void bn_relu_nchw(const u16* __restrict__ cvout, float* __restrict__ out,
                             const float* __restrict__ stats) {
    const int b = blockIdx.x;            // 256 ch * 49 groups
    const int ch = b / 49, g = b - ch * 49;
    const float inv = stats[2 * ch], sh = stats[2 * ch + 1];
    const int p8 = (g * 256 + threadIdx.x) * 8;
    short8 v = *(const short8*)&cvout[(size_t)ch * PIX + p8];
    const int n = p8 / HW2;
    const int hw = p8 - n * HW2;
    float* dst = out + ((size_t)n * K_OUT + ch) * HW2 + hw;
    f32x4 o0, o1;
    #pragma unroll
    for (int j = 0; j < 4; ++j) {
        float a = __uint_as_float(((u32)(u16)v[j]) << 16);
        float bb = __uint_as_float(((u32)(u16)v[j + 4]) << 16);
        o0[j] = fmaxf(a * inv + sh, 0.f);
        o1[j] = fmaxf(bb * inv + sh, 0.f);
    }
    *(f32x4*)dst = o0;
    *(f32x4*)(dst + 4) = o1;
}

__global__ void bn_relu_f32(float* __restrict__ out, const float* __restrict__ stats) {
    const int n4 = ((size_t)N_IMG * K_OUT * HW2) / 4;
    int stride = gridDim.x * blockDim.x;
    for (int i = blockIdx.x * blockDim.x + threadIdx.x; i < n4; i += stride) {
        int ch = (i / (HW2 / 4)) & (K_OUT - 1);
        float inv = stats[2 * ch], sh = stats[2 * ch + 1];
        f32x4 v = ((f32x4*)out)[i];
        #pragma unroll
        for (int j = 0; j < 4; ++j)
            v[j] = fmaxf(v[j] * inv + sh, 0.f);
        ((f32x4*)out)[i] = v;
    }
}

extern "C" void kernel_launch(void* const* d_in, const int* in_sizes, int n_in,
                              void* d_out, int out_size, void* d_ws, size_t ws_size,
                              hipStream_t stream) {
    const float* x = (const float*)d_in[0];
    const float* w = (const float*)d_in[1];
    const float* gamma = (const float*)d_in[2];
    const float* beta = (const float*)d_in[3];
    float* out = (float*)d_out;

    char* ws = (char*)d_ws;
    u32* wsmax = (u32*)ws;                         // [0,64)
    float* stats = (float*)(ws + 64);              // 2KB
    u16* wqt = (u16*)(ws + 4096);                  // 589,824 B
    float* P = (float*)(ws + 1048576u);            // 3,211,264 B
    u16* xt3 = (u16*)(ws + 4325376u);              // 27,795,456 B (ends 32,120,832)
    u16* cvout = (u16*)(ws + CV_OFF);              // 51,380,224 B
    const bool bf16path = (ws_size >= WS_NEED_BF16);

    hipMemsetAsync(wsmax, 0, 64, stream);
    maxabs_k<<<128, 256, 0, stream>>>(w, wsmax);
    quant_t_k5<<<WQ_N / 256, 256, 0, stream>>>(w, wsmax, wqt);
    halo_zero<<<514, 256, 0, stream>>>(xt3);
    pad_transpose<<<N_IMG * HWD, 256, 0, stream>>>(x, xt3);
    if (bf16path) {
        conv_m<true><<<784, 256, 0, stream>>>(xt3, wqt, out, cvout, P);
        stats_fin<<<K_OUT, 256, 0, stream>>>(P, gamma, beta, stats);
        bn_relu_nchw<<<K_OUT * 49, 256, 0, stream>>>(cvout, out, stats);
    } else {
        conv_m<false><<<784, 256, 0, stream>>>(xt3, wqt, out, cvout, P);
        stats_fin<<<K_OUT, 256, 0, stream>>>(P, gamma, beta, stats);
        bn_relu_f32<<<4096, 256, 0, stream>>>(out, stats);
    }
}